// Round 2
// baseline (4197.606 us; speedup 1.0000x reference)
//
#include <hip/hip_runtime.h>
#include <hip/hip_bf16.h>

#define TLEN 16384
#define NB 4
#define NLAYER 50
#define SUMD 5115
#define LOUT 11269                  // TLEN - SUMD
#define K1 (NLAYER * 32)            // 1600
#define MSKIP 512

typedef unsigned short u16;
typedef __attribute__((ext_vector_type(4))) float f32x4;
typedef __attribute__((ext_vector_type(8))) __bf16 bf16x8;

__device__ __forceinline__ u16 f2bf(float f) {
  __hip_bfloat16 h = __float2bfloat16(f);
  return *reinterpret_cast<u16*>(&h);
}
__device__ __forceinline__ float bf2f(u16 u) {
  __hip_bfloat16 h = *reinterpret_cast<__hip_bfloat16*>(&u);
  return __bfloat162float(h);
}

// ---------- prep: convert/pack weights (once per call) ----------
// Wskip[m][i*32+c] = skip_w[i][m][c] (bf16); P1 = bf16(post1_w); biasS[c] = sum_i skip_b[i][c]
__global__ __launch_bounds__(256) void prep_k(
    const float* __restrict__ skip_w, const float* __restrict__ skip_b,
    const float* __restrict__ post1_w,
    u16* __restrict__ Wskip, u16* __restrict__ P1, float* __restrict__ biasS) {
  int t = blockIdx.x * 256 + threadIdx.x;
  const int n1 = 512 * K1;          // 819200
  const int n2 = n1 + 512 * 512;    // +262144
  if (t < n1) {
    int m = t / K1, k = t - m * K1;
    int i = k >> 5, c = k & 31;
    Wskip[t] = f2bf(skip_w[((size_t)i * 512 + m) * 32 + c]);
  } else if (t < n2) {
    int z = t - n1;
    P1[z] = f2bf(post1_w[z]);
  } else if (t < n2 + 512) {
    int c = t - n2;
    float s = 0.f;
    for (int i = 0; i < NLAYER; i++) s += skip_b[i * 512 + c];
    biasS[c] = s;
  }
}

// ---------- h0 = from_w @ input^T + from_b, over window [t0, t0+cw) ----------
__global__ __launch_bounds__(256) void init_h(
    const float* __restrict__ inp, const float* __restrict__ fw,
    const float* __restrict__ fb, float* __restrict__ H, int t0, int cw) {
  int b = blockIdx.y;
  int p = blockIdx.x * 256 + threadIdx.x;   // 0..cw-1 (buffer index)
  if (p >= cw) return;
  const float* ip = inp + ((size_t)b * TLEN + t0 + p) * 8;
  float4 x0 = *reinterpret_cast<const float4*>(ip);
  float4 x1 = *reinterpret_cast<const float4*>(ip + 4);
  float x[8] = {x0.x, x0.y, x0.z, x0.w, x1.x, x1.y, x1.z, x1.w};
  float* hb = H + (size_t)b * 32 * cw;
  #pragma unroll
  for (int r = 0; r < 32; r++) {
    float acc = fb[r];
    #pragma unroll
    for (int f = 0; f < 8; f++) acc += fw[r * 8 + f] * x[f];
    hb[(size_t)r * cw + p] = acc;
  }
}

// ---------- one WaveNet layer (right-aligned window of length cw, ping-pong) ----------
// outputs p in [cw-len_out, cw): gate from Hin[p-d], Hin[p];
// Hout[p] = res_w@gate + res_b + Hin[p]; gates (bf16) -> G[n][layer*32..] for p >= cw-clen
__global__ __launch_bounds__(256) void layer_k(
    const float* __restrict__ Hin, float* __restrict__ Hout,
    u16* __restrict__ G,
    const float* __restrict__ sw, const float* __restrict__ sb,
    const float* __restrict__ tw, const float* __restrict__ tb,
    const float* __restrict__ rw, const float* __restrict__ rb,
    int layer, int d, int len_out, int cw, int clen) {
  int b = blockIdx.y;
  int idx = blockIdx.x * 256 + threadIdx.x;
  bool valid = idx < len_out;
  int p = cw - len_out + (valid ? idx : 0);
  const float* hb = Hin + (size_t)b * 32 * cw;

  float hL[32], hR[32];
  #pragma unroll
  for (int r = 0; r < 32; r++) {
    hL[r] = hb[(size_t)r * cw + p - d];
    hR[r] = hb[(size_t)r * cw + p];
  }

  const float* swl = sw + (size_t)layer * 2048;
  const float* twl = tw + (size_t)layer * 2048;
  const float* sbl = sb + layer * 32;
  const float* tbl = tb + layer * 32;

  float gate[32];
  #pragma unroll
  for (int o = 0; o < 32; o++) {
    float ss = sbl[o], tt = tbl[o];
    #pragma unroll
    for (int c = 0; c < 32; c++) {
      ss += swl[o * 64 + c * 2] * hL[c] + swl[o * 64 + c * 2 + 1] * hR[c];
      tt += twl[o * 64 + c * 2] * hL[c] + twl[o * 64 + c * 2 + 1] * hR[c];
    }
    float sig = 1.f / (1.f + __expf(-ss));
    float th  = 2.f / (1.f + __expf(-2.f * tt)) - 1.f;
    gate[o] = sig * th;
  }

  // gates -> G ([n][K1] bf16), 64B per thread via 4x dwordx4 stores
  if (valid && p >= cw - clen) {
    int n = b * clen + (p - (cw - clen));
    uint4* gp4 = reinterpret_cast<uint4*>(G + (size_t)n * K1 + layer * 32);
    #define PK(i) ((unsigned)f2bf(gate[2*(i)]) | ((unsigned)f2bf(gate[2*(i)+1]) << 16))
    uint4 v0 = {PK(0), PK(1), PK(2), PK(3)};
    uint4 v1 = {PK(4), PK(5), PK(6), PK(7)};
    uint4 v2 = {PK(8), PK(9), PK(10), PK(11)};
    uint4 v3 = {PK(12), PK(13), PK(14), PK(15)};
    #undef PK
    gp4[0] = v0; gp4[1] = v1; gp4[2] = v2; gp4[3] = v3;
  }

  // residual update
  const float* rwl = rw + (size_t)layer * 1024;
  const float* rbl = rb + layer * 32;
  float* ho = Hout + (size_t)b * 32 * cw;
  #pragma unroll
  for (int o = 0; o < 32; o++) {
    float acc = rbl[o];
    #pragma unroll
    for (int c = 0; c < 32; c++) acc += rwl[o * 32 + c] * gate[c];
    if (valid) ho[(size_t)o * cw + p] = acc + hR[o];
  }
}

// ---------- bf16 MFMA GEMM: Out[m][n] = bf16(elu(sum_k A[m][k]*B[k][n] + bias[m])) ----------
// A: [512][K] bf16 row-major. B: BT ? [N][K] : [K][N]. grid (ceil(N/128), 4), 256 thr.
__global__ __launch_bounds__(256) void gemm_k(
    const u16* __restrict__ A, const u16* __restrict__ B,
    const float* __restrict__ bias, u16* __restrict__ Out,
    int N, int K, int BT) {
  __shared__ u16 As[128][40];
  __shared__ u16 Bs[128][40];
  int tid = threadIdx.x;
  int n0 = blockIdx.x * 128, m0 = blockIdx.y * 128;
  int lane = tid & 63, w = tid >> 6;
  int wm = w >> 1, wn = w & 1;

  f32x4 acc[4][4];
  #pragma unroll
  for (int i = 0; i < 4; i++)
    #pragma unroll
    for (int j = 0; j < 4; j++) acc[i][j] = f32x4{0.f, 0.f, 0.f, 0.f};

  for (int k0 = 0; k0 < K; k0 += 32) {
    {  // stage A tile [128][32]
      int r = tid >> 1, half = tid & 1;
      const uint4* asrc = reinterpret_cast<const uint4*>(A + (size_t)(m0 + r) * K + k0 + half * 16);
      uint4 a0 = asrc[0], a1 = asrc[1];
      *reinterpret_cast<uint4*>(&As[r][half * 16]) = a0;
      *reinterpret_cast<uint4*>(&As[r][half * 16 + 8]) = a1;
    }
    if (BT) {
      int r = tid >> 1, half = tid & 1;
      int nr = n0 + r;
      uint4 b0 = {0, 0, 0, 0}, b1 = {0, 0, 0, 0};
      if (nr < N) {
        const uint4* bsrc = reinterpret_cast<const uint4*>(B + (size_t)nr * K + k0 + half * 16);
        b0 = bsrc[0]; b1 = bsrc[1];
      }
      *reinterpret_cast<uint4*>(&Bs[r][half * 16]) = b0;
      *reinterpret_cast<uint4*>(&Bs[r][half * 16 + 8]) = b1;
    } else {
      // B is [K][N]: transpose 32x128 into Bs
      int kk = tid >> 3, seg = tid & 7;
      int nbase = n0 + seg * 16;
      const u16* bsrc = B + (size_t)(k0 + kk) * N + nbase;
      u16 tmp[16];
      if (nbase + 16 <= N) {
        const uint2* q = reinterpret_cast<const uint2*>(bsrc);  // 8B-aligned rows
        uint2 v0 = q[0], v1 = q[1], v2 = q[2], v3 = q[3];
        tmp[0] = v0.x & 0xffff; tmp[1] = v0.x >> 16; tmp[2] = v0.y & 0xffff; tmp[3] = v0.y >> 16;
        tmp[4] = v1.x & 0xffff; tmp[5] = v1.x >> 16; tmp[6] = v1.y & 0xffff; tmp[7] = v1.y >> 16;
        tmp[8] = v2.x & 0xffff; tmp[9] = v2.x >> 16; tmp[10] = v2.y & 0xffff; tmp[11] = v2.y >> 16;
        tmp[12] = v3.x & 0xffff; tmp[13] = v3.x >> 16; tmp[14] = v3.y & 0xffff; tmp[15] = v3.y >> 16;
      } else {
        #pragma unroll
        for (int e = 0; e < 16; e++) tmp[e] = (nbase + e < N) ? bsrc[e] : (u16)0;
      }
      #pragma unroll
      for (int e = 0; e < 16; e++) Bs[seg * 16 + e][kk] = tmp[e];
    }
    __syncthreads();

    int row16 = lane & 15, kg = lane >> 4;
    bf16x8 af[4], bfr[4];
    #pragma unroll
    for (int mf = 0; mf < 4; mf++)
      af[mf] = *reinterpret_cast<const bf16x8*>(&As[wm * 64 + mf * 16 + row16][kg * 8]);
    #pragma unroll
    for (int nf = 0; nf < 4; nf++)
      bfr[nf] = *reinterpret_cast<const bf16x8*>(&Bs[wn * 64 + nf * 16 + row16][kg * 8]);
    #pragma unroll
    for (int mf = 0; mf < 4; mf++)
      #pragma unroll
      for (int nf = 0; nf < 4; nf++)
        acc[mf][nf] = __builtin_amdgcn_mfma_f32_16x16x32_bf16(af[mf], bfr[nf], acc[mf][nf], 0, 0, 0);
    __syncthreads();
  }

  // epilogue: bias + elu -> bf16 (Out row-major [512][N])
  #pragma unroll
  for (int mf = 0; mf < 4; mf++) {
    #pragma unroll
    for (int nf = 0; nf < 4; nf++) {
      #pragma unroll
      for (int r = 0; r < 4; r++) {
        int row = m0 + wm * 64 + mf * 16 + (lane >> 4) * 4 + r;
        int col = n0 + wn * 64 + nf * 16 + (lane & 15);
        float v = acc[mf][nf][r] + bias[row];
        float e = v > 0.f ? v : expm1f(v);
        if (col < N) Out[(size_t)row * N + col] = f2bf(e);
      }
    }
  }
}

// ---------- final: out[b*LOUT + t0 + tc] = post2_w . E2[:, n] + post2_b ----------
__global__ __launch_bounds__(256) void final_k(
    const u16* __restrict__ E2, const float* __restrict__ w,
    const float* __restrict__ bptr, float* __restrict__ out,
    int Nc, int clen, int t0) {
  int n = blockIdx.x * 256 + threadIdx.x;
  if (n >= Nc) return;
  float acc = bptr[0];
  #pragma unroll 8
  for (int c = 0; c < 512; c++) acc += w[c] * bf2f(E2[(size_t)c * Nc + n]);
  int b = n / clen, tc = n - b * clen;
  out[(size_t)b * LOUT + t0 + tc] = acc;
}

extern "C" void kernel_launch(void* const* d_in, const int* in_sizes, int n_in,
                              void* d_out, int out_size, void* d_ws, size_t ws_size,
                              hipStream_t stream) {
  const float* input   = (const float*)d_in[0];
  const float* from_w  = (const float*)d_in[1];
  const float* from_b  = (const float*)d_in[2];
  const float* sig_w   = (const float*)d_in[3];
  const float* sig_b   = (const float*)d_in[4];
  const float* tan_w   = (const float*)d_in[5];
  const float* tan_b   = (const float*)d_in[6];
  const float* skip_w  = (const float*)d_in[7];
  const float* skip_b  = (const float*)d_in[8];
  const float* res_w   = (const float*)d_in[9];
  const float* res_b   = (const float*)d_in[10];
  const float* post1_w = (const float*)d_in[11];
  const float* post1_b = (const float*)d_in[12];
  const float* post2_w = (const float*)d_in[13];
  const float* post2_b = (const float*)d_in[14];

  // ---- runtime layout: weights region, then chunk-sized H0/H1/G/E ----
  auto al = [](size_t x) { return (x + 255) & ~(size_t)255; };
  size_t oW  = 0;
  size_t oP1 = oW  + al((size_t)512 * K1 * 2);
  size_t oB  = oP1 + al((size_t)512 * 512 * 2);
  size_t wend = oB + al((size_t)512 * 4);

  // pick smallest chunk count whose footprint fits ws_size
  int NC = 32, CL = 0, CWMAX = 0;
  size_t oH0 = wend, oH1 = wend, oG = wend, oE = wend;
  const int cand[6] = {1, 2, 4, 8, 16, 32};
  for (int ci = 0; ci < 6; ci++) {
    int nc = cand[ci];
    int cl = (LOUT + nc - 1) / nc;
    int cw = cl + SUMD;
    size_t hB = al((size_t)NB * 32 * cw * 4);
    size_t gB = al((size_t)NB * cl * K1 * 2);
    size_t eB = al((size_t)512 * NB * cl * 2);
    size_t need = wend + 2 * hB + gB + eB;
    if (need <= ws_size || nc == 32) {
      NC = nc; CL = cl; CWMAX = cw;
      oH0 = wend; oH1 = oH0 + hB; oG = oH1 + hB; oE = oG + gB;
      break;
    }
  }
  (void)CWMAX;

  char* ws = (char*)d_ws;
  u16*   Wskip = (u16*)(ws + oW);
  u16*   P1    = (u16*)(ws + oP1);
  float* biasS = (float*)(ws + oB);
  float* H0    = (float*)(ws + oH0);
  float* H1    = (float*)(ws + oH1);
  u16*   G     = (u16*)(ws + oG);
  u16*   E     = (u16*)(ws + oE);
  u16*   E2    = (u16*)(ws + oG);   // reuse G (dead after GEMM1)

  int prep_items = 512 * K1 + 512 * 512 + 512;
  prep_k<<<(prep_items + 255) / 256, 256, 0, stream>>>(skip_w, skip_b, post1_w, Wskip, P1, biasS);

  int dils[NLAYER];
  for (int rep = 0; rep < 5; rep++)
    for (int j = 0; j < 10; j++) dils[rep * 10 + j] = 1 << j;

  for (int c = 0; c < NC; c++) {
    int t0 = c * CL;
    if (t0 >= LOUT) break;               // deterministic given fixed ws_size
    int clen = LOUT - t0 < CL ? LOUT - t0 : CL;
    int cw = clen + SUMD;

    init_h<<<dim3((cw + 255) / 256, NB), 256, 0, stream>>>(input, from_w, from_b, H0, t0, cw);

    int len = cw;
    float* a = H0;
    float* b = H1;
    for (int i = 0; i < NLAYER; i++) {
      int d = dils[i];
      int lo = len - d;
      layer_k<<<dim3((lo + 255) / 256, NB), 256, 0, stream>>>(
          a, b, G, sig_w, sig_b, tan_w, tan_b, res_w, res_b, i, d, lo, cw, clen);
      len = lo;
      float* t = a; a = b; b = t;
    }

    int Nc = NB * clen;
    // skip GEMM: E = elu(Wskip @ G^T + biasS)     (BT layout)
    gemm_k<<<dim3((Nc + 127) / 128, MSKIP / 128), 256, 0, stream>>>(Wskip, G, biasS, E, Nc, K1, 1);
    // post1 GEMM: E2 = elu(P1 @ E + post1_b)      (B = [K][N] layout)
    gemm_k<<<dim3((Nc + 127) / 128, MSKIP / 128), 256, 0, stream>>>(P1, E, post1_b, E2, Nc, 512, 0);

    final_k<<<(Nc + 255) / 256, 256, 0, stream>>>(E2, post2_w, post2_b, (float*)d_out, Nc, clen, t0);
  }
}

// Round 3
// 1698.812 us; speedup vs baseline: 2.4709x; 2.4709x over previous
//
#include <hip/hip_runtime.h>
#include <hip/hip_bf16.h>

#define TLEN 16384
#define NB 4
#define NLAYER 50
#define SUMD 5115
#define LOUT 11269                  // TLEN - SUMD
#define K1 (NLAYER * 32)            // 1600
#define MSKIP 512
#define LPTS 128                    // points per layer block

typedef unsigned short u16;
typedef __attribute__((ext_vector_type(4))) float f32x4;
typedef __attribute__((ext_vector_type(8))) __bf16 bf16x8;

__device__ __forceinline__ u16 f2bf(float f) {
  __hip_bfloat16 h = __float2bfloat16(f);
  return *reinterpret_cast<u16*>(&h);
}
__device__ __forceinline__ float bf2f(u16 u) {
  __hip_bfloat16 h = *reinterpret_cast<__hip_bfloat16*>(&u);
  return __bfloat162float(h);
}

// ---------- prep: convert/pack weights (once per call) ----------
__global__ __launch_bounds__(256) void prep_k(
    const float* __restrict__ skip_w, const float* __restrict__ skip_b,
    const float* __restrict__ post1_w,
    u16* __restrict__ Wskip, u16* __restrict__ P1, float* __restrict__ biasS) {
  int t = blockIdx.x * 256 + threadIdx.x;
  const int n1 = 512 * K1;          // 819200
  const int n2 = n1 + 512 * 512;    // +262144
  if (t < n1) {
    int m = t / K1, k = t - m * K1;
    int i = k >> 5, c = k & 31;
    Wskip[t] = f2bf(skip_w[((size_t)i * 512 + m) * 32 + c]);
  } else if (t < n2) {
    int z = t - n1;
    P1[z] = f2bf(post1_w[z]);
  } else if (t < n2 + 512) {
    int c = t - n2;
    float s = 0.f;
    for (int i = 0; i < NLAYER; i++) s += skip_b[i * 512 + c];
    biasS[c] = s;
  }
}

// ---------- h0 = from_w @ input^T + from_b, over window [t0, t0+cw) ----------
__global__ __launch_bounds__(256) void init_h(
    const float* __restrict__ inp, const float* __restrict__ fw,
    const float* __restrict__ fb, float* __restrict__ H, int t0, int cw) {
  int b = blockIdx.y;
  int p = blockIdx.x * 256 + threadIdx.x;
  if (p >= cw) return;
  const float* ip = inp + ((size_t)b * TLEN + t0 + p) * 8;
  float4 x0 = *reinterpret_cast<const float4*>(ip);
  float4 x1 = *reinterpret_cast<const float4*>(ip + 4);
  float x[8] = {x0.x, x0.y, x0.z, x0.w, x1.x, x1.y, x1.z, x1.w};
  float* hb = H + (size_t)b * 32 * cw;
  #pragma unroll
  for (int r = 0; r < 32; r++) {
    float acc = fb[r];
    #pragma unroll
    for (int f = 0; f < 8; f++) acc += fw[r * 8 + f] * x[f];
    hb[(size_t)r * cw + p] = acc;
  }
}

// ---------- one WaveNet layer: LDS-staged weights, 2 threads/point ----------
// block = 256 thr: 128 points x 2 output-halves. Waves are half-uniform
// (lanes 0..63 => g=0), so weight reads are LDS broadcasts.
__global__ __launch_bounds__(256) void layer_k(
    const float* __restrict__ Hin, float* __restrict__ Hout,
    u16* __restrict__ G,
    const float* __restrict__ sw, const float* __restrict__ sb,
    const float* __restrict__ tw, const float* __restrict__ tb,
    const float* __restrict__ rw, const float* __restrict__ rb,
    int layer, int d, int len_out, int cw, int clen) {
  __shared__ float4 WS4[512];      // sig_w layer slice: [o][c*2+lr] as float4
  __shared__ float4 WT4[512];      // tan_w
  __shared__ float4 WR4[256];      // res_w [o][c] as float4
  __shared__ float BS[32], BTA[32], BR[32];
  __shared__ float GL[LPTS][33];   // gate exchange, +1 pad

  int tid = threadIdx.x;
  // ---- cooperative weight staging ----
  {
    const float4* swl = reinterpret_cast<const float4*>(sw + (size_t)layer * 2048);
    const float4* twl = reinterpret_cast<const float4*>(tw + (size_t)layer * 2048);
    const float4* rwl = reinterpret_cast<const float4*>(rw + (size_t)layer * 1024);
    WS4[tid] = swl[tid];
    WS4[tid + 256] = swl[tid + 256];
    WT4[tid] = twl[tid];
    WT4[tid + 256] = twl[tid + 256];
    WR4[tid] = rwl[tid];
    if (tid < 32) {
      BS[tid]  = sb[layer * 32 + tid];
      BTA[tid] = tb[layer * 32 + tid];
      BR[tid]  = rb[layer * 32 + tid];
    }
  }

  int b = blockIdx.y;
  int g  = tid >> 7;               // output half: o in [g*16, g*16+16)
  int li = tid & 127;              // point within block
  int idx = blockIdx.x * LPTS + li;
  bool valid = idx < len_out;
  int p = cw - len_out + (valid ? idx : 0);
  const float* hb = Hin + (size_t)b * 32 * cw;

  float hL[32], hR[32];
  #pragma unroll
  for (int r = 0; r < 32; r++) {
    hL[r] = hb[(size_t)r * cw + p - d];
    hR[r] = hb[(size_t)r * cw + p];
  }
  __syncthreads();                 // weights staged

  // ---- gates for this thread's 16 outputs ----
  int ob = g * 16;
  float gate[16];
  #pragma unroll
  for (int oi = 0; oi < 16; oi++) {
    int o = ob + oi;
    float ss = BS[o], tt = BTA[o];
    #pragma unroll
    for (int c4 = 0; c4 < 16; c4++) {
      float4 wsv = WS4[o * 16 + c4];
      float4 wtv = WT4[o * 16 + c4];
      int c = c4 * 2;
      ss += wsv.x * hL[c] + wsv.y * hR[c] + wsv.z * hL[c + 1] + wsv.w * hR[c + 1];
      tt += wtv.x * hL[c] + wtv.y * hR[c] + wtv.z * hL[c + 1] + wtv.w * hR[c + 1];
    }
    float sig = 1.f / (1.f + __expf(-ss));
    float th  = 2.f / (1.f + __expf(-2.f * tt)) - 1.f;
    gate[oi] = sig * th;
  }

  // ---- exchange gates via LDS; store G (bf16) ----
  #pragma unroll
  for (int oi = 0; oi < 16; oi++) GL[li][ob + oi] = gate[oi];

  if (valid && p >= cw - clen) {
    int n = b * clen + (p - (cw - clen));
    uint4* gp = reinterpret_cast<uint4*>(G + (size_t)n * K1 + layer * 32 + ob);
    #define PK(i) ((unsigned)f2bf(gate[2*(i)]) | ((unsigned)f2bf(gate[2*(i)+1]) << 16))
    uint4 v0 = {PK(0), PK(1), PK(2), PK(3)};
    uint4 v1 = {PK(4), PK(5), PK(6), PK(7)};
    #undef PK
    gp[0] = v0; gp[1] = v1;
  }
  __syncthreads();                 // gates visible

  // ---- residual update for this thread's 16 outputs ----
  float gv[32];
  #pragma unroll
  for (int c = 0; c < 32; c++) gv[c] = GL[li][c];

  float* ho = Hout + (size_t)b * 32 * cw;
  #pragma unroll
  for (int oi = 0; oi < 16; oi++) {
    int o = ob + oi;
    float acc = BR[o];
    #pragma unroll
    for (int c4 = 0; c4 < 8; c4++) {
      float4 wv = WR4[o * 8 + c4];
      int c = c4 * 4;
      acc += wv.x * gv[c] + wv.y * gv[c + 1] + wv.z * gv[c + 2] + wv.w * gv[c + 3];
    }
    if (valid) ho[(size_t)o * cw + p] = acc + hR[o];
  }
}

// ---------- bf16 MFMA GEMM: Out[m][n] = bf16(elu(sum_k A[m][k]*B[k][n] + bias[m])) ----------
__global__ __launch_bounds__(256) void gemm_k(
    const u16* __restrict__ A, const u16* __restrict__ B,
    const float* __restrict__ bias, u16* __restrict__ Out,
    int N, int K, int BT) {
  __shared__ u16 As[128][40];
  __shared__ u16 Bs[128][40];
  int tid = threadIdx.x;
  int n0 = blockIdx.x * 128, m0 = blockIdx.y * 128;
  int lane = tid & 63, w = tid >> 6;
  int wm = w >> 1, wn = w & 1;

  f32x4 acc[4][4];
  #pragma unroll
  for (int i = 0; i < 4; i++)
    #pragma unroll
    for (int j = 0; j < 4; j++) acc[i][j] = f32x4{0.f, 0.f, 0.f, 0.f};

  for (int k0 = 0; k0 < K; k0 += 32) {
    {
      int r = tid >> 1, half = tid & 1;
      const uint4* asrc = reinterpret_cast<const uint4*>(A + (size_t)(m0 + r) * K + k0 + half * 16);
      uint4 a0 = asrc[0], a1 = asrc[1];
      *reinterpret_cast<uint4*>(&As[r][half * 16]) = a0;
      *reinterpret_cast<uint4*>(&As[r][half * 16 + 8]) = a1;
    }
    if (BT) {
      int r = tid >> 1, half = tid & 1;
      int nr = n0 + r;
      uint4 b0 = {0, 0, 0, 0}, b1 = {0, 0, 0, 0};
      if (nr < N) {
        const uint4* bsrc = reinterpret_cast<const uint4*>(B + (size_t)nr * K + k0 + half * 16);
        b0 = bsrc[0]; b1 = bsrc[1];
      }
      *reinterpret_cast<uint4*>(&Bs[r][half * 16]) = b0;
      *reinterpret_cast<uint4*>(&Bs[r][half * 16 + 8]) = b1;
    } else {
      int kk = tid >> 3, seg = tid & 7;
      int nbase = n0 + seg * 16;
      const u16* bsrc = B + (size_t)(k0 + kk) * N + nbase;
      u16 tmp[16];
      if (nbase + 16 <= N) {
        const uint2* q = reinterpret_cast<const uint2*>(bsrc);
        uint2 v0 = q[0], v1 = q[1], v2 = q[2], v3 = q[3];
        tmp[0] = v0.x & 0xffff; tmp[1] = v0.x >> 16; tmp[2] = v0.y & 0xffff; tmp[3] = v0.y >> 16;
        tmp[4] = v1.x & 0xffff; tmp[5] = v1.x >> 16; tmp[6] = v1.y & 0xffff; tmp[7] = v1.y >> 16;
        tmp[8] = v2.x & 0xffff; tmp[9] = v2.x >> 16; tmp[10] = v2.y & 0xffff; tmp[11] = v2.y >> 16;
        tmp[12] = v3.x & 0xffff; tmp[13] = v3.x >> 16; tmp[14] = v3.y & 0xffff; tmp[15] = v3.y >> 16;
      } else {
        #pragma unroll
        for (int e = 0; e < 16; e++) tmp[e] = (nbase + e < N) ? bsrc[e] : (u16)0;
      }
      #pragma unroll
      for (int e = 0; e < 16; e++) Bs[seg * 16 + e][kk] = tmp[e];
    }
    __syncthreads();

    int row16 = lane & 15, kg = lane >> 4;
    bf16x8 af[4], bfr[4];
    #pragma unroll
    for (int mf = 0; mf < 4; mf++)
      af[mf] = *reinterpret_cast<const bf16x8*>(&As[wm * 64 + mf * 16 + row16][kg * 8]);
    #pragma unroll
    for (int nf = 0; nf < 4; nf++)
      bfr[nf] = *reinterpret_cast<const bf16x8*>(&Bs[wn * 64 + nf * 16 + row16][kg * 8]);
    #pragma unroll
    for (int mf = 0; mf < 4; mf++)
      #pragma unroll
      for (int nf = 0; nf < 4; nf++)
        acc[mf][nf] = __builtin_amdgcn_mfma_f32_16x16x32_bf16(af[mf], bfr[nf], acc[mf][nf], 0, 0, 0);
    __syncthreads();
  }

  #pragma unroll
  for (int mf = 0; mf < 4; mf++) {
    #pragma unroll
    for (int nf = 0; nf < 4; nf++) {
      #pragma unroll
      for (int r = 0; r < 4; r++) {
        int row = m0 + wm * 64 + mf * 16 + (lane >> 4) * 4 + r;
        int col = n0 + wn * 64 + nf * 16 + (lane & 15);
        float v = acc[mf][nf][r] + bias[row];
        float e = v > 0.f ? v : expm1f(v);
        if (col < N) Out[(size_t)row * N + col] = f2bf(e);
      }
    }
  }
}

// ---------- final: out[b*LOUT + t0 + tc] = post2_w . E2[:, n] + post2_b ----------
__global__ __launch_bounds__(256) void final_k(
    const u16* __restrict__ E2, const float* __restrict__ w,
    const float* __restrict__ bptr, float* __restrict__ out,
    int Nc, int clen, int t0) {
  int n = blockIdx.x * 256 + threadIdx.x;
  if (n >= Nc) return;
  float acc = bptr[0];
  #pragma unroll 8
  for (int c = 0; c < 512; c++) acc += w[c] * bf2f(E2[(size_t)c * Nc + n]);
  int b = n / clen, tc = n - b * clen;
  out[(size_t)b * LOUT + t0 + tc] = acc;
}

extern "C" void kernel_launch(void* const* d_in, const int* in_sizes, int n_in,
                              void* d_out, int out_size, void* d_ws, size_t ws_size,
                              hipStream_t stream) {
  const float* input   = (const float*)d_in[0];
  const float* from_w  = (const float*)d_in[1];
  const float* from_b  = (const float*)d_in[2];
  const float* sig_w   = (const float*)d_in[3];
  const float* sig_b   = (const float*)d_in[4];
  const float* tan_w   = (const float*)d_in[5];
  const float* tan_b   = (const float*)d_in[6];
  const float* skip_w  = (const float*)d_in[7];
  const float* skip_b  = (const float*)d_in[8];
  const float* res_w   = (const float*)d_in[9];
  const float* res_b   = (const float*)d_in[10];
  const float* post1_w = (const float*)d_in[11];
  const float* post1_b = (const float*)d_in[12];
  const float* post2_w = (const float*)d_in[13];
  const float* post2_b = (const float*)d_in[14];

  auto al = [](size_t x) { return (x + 255) & ~(size_t)255; };
  size_t oW  = 0;
  size_t oP1 = oW  + al((size_t)512 * K1 * 2);
  size_t oB  = oP1 + al((size_t)512 * 512 * 2);
  size_t wend = oB + al((size_t)512 * 4);

  int NC = 32, CL = 0;
  size_t oH0 = wend, oH1 = wend, oG = wend, oE = wend;
  const int cand[6] = {1, 2, 4, 8, 16, 32};
  for (int ci = 0; ci < 6; ci++) {
    int nc = cand[ci];
    int cl = (LOUT + nc - 1) / nc;
    int cw = cl + SUMD;
    size_t hB = al((size_t)NB * 32 * cw * 4);
    size_t gB = al((size_t)NB * cl * K1 * 2);
    size_t eB = al((size_t)512 * NB * cl * 2);
    size_t need = wend + 2 * hB + gB + eB;
    if (need <= ws_size || nc == 32) {
      NC = nc; CL = cl;
      oH0 = wend; oH1 = oH0 + hB; oG = oH1 + hB; oE = oG + gB;
      break;
    }
  }

  char* ws = (char*)d_ws;
  u16*   Wskip = (u16*)(ws + oW);
  u16*   P1    = (u16*)(ws + oP1);
  float* biasS = (float*)(ws + oB);
  float* H0    = (float*)(ws + oH0);
  float* H1    = (float*)(ws + oH1);
  u16*   G     = (u16*)(ws + oG);
  u16*   E     = (u16*)(ws + oE);
  u16*   E2    = (u16*)(ws + oG);   // reuse G (dead after GEMM1)

  int prep_items = 512 * K1 + 512 * 512 + 512;
  prep_k<<<(prep_items + 255) / 256, 256, 0, stream>>>(skip_w, skip_b, post1_w, Wskip, P1, biasS);

  int dils[NLAYER];
  for (int rep = 0; rep < 5; rep++)
    for (int j = 0; j < 10; j++) dils[rep * 10 + j] = 1 << j;

  for (int c = 0; c < NC; c++) {
    int t0 = c * CL;
    if (t0 >= LOUT) break;
    int clen = LOUT - t0 < CL ? LOUT - t0 : CL;
    int cw = clen + SUMD;

    init_h<<<dim3((cw + 255) / 256, NB), 256, 0, stream>>>(input, from_w, from_b, H0, t0, cw);

    int len = cw;
    float* a = H0;
    float* b = H1;
    for (int i = 0; i < NLAYER; i++) {
      int d = dils[i];
      int lo = len - d;
      layer_k<<<dim3((lo + LPTS - 1) / LPTS, NB), 256, 0, stream>>>(
          a, b, G, sig_w, sig_b, tan_w, tan_b, res_w, res_b, i, d, lo, cw, clen);
      len = lo;
      float* t = a; a = b; b = t;
    }

    int Nc = NB * clen;
    gemm_k<<<dim3((Nc + 127) / 128, MSKIP / 128), 256, 0, stream>>>(Wskip, G, biasS, E, Nc, K1, 1);
    gemm_k<<<dim3((Nc + 127) / 128, MSKIP / 128), 256, 0, stream>>>(P1, E, post1_b, E2, Nc, 512, 0);

    final_k<<<(Nc + 255) / 256, 256, 0, stream>>>(E2, post2_w, post2_b, (float*)d_out, Nc, clen, t0);
  }
}

// Round 4
// 989.685 us; speedup vs baseline: 4.2414x; 1.7165x over previous
//
#include <hip/hip_runtime.h>
#include <hip/hip_bf16.h>

#define TLEN 16384
#define NB 4
#define NLAYER 50
#define SUMD 5115
#define LOUT 11269                  // TLEN - SUMD
#define K1 (NLAYER * 32)            // 1600
#define MSKIP 512

typedef unsigned short u16;
typedef __attribute__((ext_vector_type(4))) float f32x4;
typedef __attribute__((ext_vector_type(8))) __bf16 bf16x8;

__device__ __forceinline__ u16 f2bf(float f) {
  __hip_bfloat16 h = __float2bfloat16(f);
  return *reinterpret_cast<u16*>(&h);
}
__device__ __forceinline__ float bf2f(u16 u) {
  __hip_bfloat16 h = *reinterpret_cast<__hip_bfloat16*>(&u);
  return __bfloat162float(h);
}

// ---------- prep: convert/pack weights (once per call) ----------
// Wskip[m][i*32+c]=skip_w[i][m][c]; P1=bf16(post1_w); biasS[c]=sum_i skip_b[i][c];
// WC[l][o][k]: o<32 sig row, o>=32 tan row; k<32 -> w0[c=k] (hL), k>=32 -> w1[c=k-32] (hR)
// RC[l][o][c] = res_w[l][o][c]
__global__ __launch_bounds__(256) void prep_k(
    const float* __restrict__ skip_w, const float* __restrict__ skip_b,
    const float* __restrict__ post1_w,
    const float* __restrict__ sig_w, const float* __restrict__ tan_w,
    const float* __restrict__ res_w,
    u16* __restrict__ Wskip, u16* __restrict__ P1, float* __restrict__ biasS,
    u16* __restrict__ WC, u16* __restrict__ RC) {
  int t = blockIdx.x * 256 + threadIdx.x;
  const int n1 = 512 * K1;                 // 819200
  const int n2 = n1 + 512 * 512;           // +262144
  const int n3 = n2 + 512;
  const int n4 = n3 + NLAYER * 64 * 64;    // +204800
  const int n5 = n4 + NLAYER * 32 * 32;    // +51200
  if (t < n1) {
    int m = t / K1, k = t - m * K1;
    int i = k >> 5, c = k & 31;
    Wskip[t] = f2bf(skip_w[((size_t)i * 512 + m) * 32 + c]);
  } else if (t < n2) {
    int z = t - n1;
    P1[z] = f2bf(post1_w[z]);
  } else if (t < n3) {
    int c = t - n2;
    float s = 0.f;
    for (int i = 0; i < NLAYER; i++) s += skip_b[i * 512 + c];
    biasS[c] = s;
  } else if (t < n4) {
    int z = t - n3;
    int l = z >> 12, rem = z & 4095, o = rem >> 6, k = rem & 63;
    int c = k & 31, lr = k >> 5;
    float v;
    if (o < 32) v = sig_w[(((size_t)l * 32 + o) * 32 + c) * 2 + lr];
    else        v = tan_w[(((size_t)l * 32 + (o - 32)) * 32 + c) * 2 + lr];
    WC[z] = f2bf(v);
  } else if (t < n5) {
    int z = t - n4;
    int l = z >> 10, rem = z & 1023, o = rem >> 5, c = rem & 31;
    RC[z] = f2bf(res_w[((size_t)l * 32 + o) * 32 + c]);
  }
}

// ---------- h0 = from_w @ input^T + from_b, over window [t0, t0+cw) ----------
__global__ __launch_bounds__(256) void init_h(
    const float* __restrict__ inp, const float* __restrict__ fw,
    const float* __restrict__ fb, float* __restrict__ H, int t0, int cw) {
  int b = blockIdx.y;
  int p = blockIdx.x * 256 + threadIdx.x;
  if (p >= cw) return;
  const float* ip = inp + ((size_t)b * TLEN + t0 + p) * 8;
  float4 x0 = *reinterpret_cast<const float4*>(ip);
  float4 x1 = *reinterpret_cast<const float4*>(ip + 4);
  float x[8] = {x0.x, x0.y, x0.z, x0.w, x1.x, x1.y, x1.z, x1.w};
  float* hb = H + (size_t)b * 32 * cw;
  #pragma unroll
  for (int r = 0; r < 32; r++) {
    float acc = fb[r];
    #pragma unroll
    for (int f = 0; f < 8; f++) acc += fw[r * 8 + f] * x[f];
    hb[(size_t)r * cw + p] = acc;
  }
}

// ---------- one WaveNet layer via MFMA ----------
// 128 thr = 2 waves; each wave owns 64 consecutive points (4 tiles of 16).
// Gates: S/T[64 out][16 pts] = Wc[64x64] @ V[64x16] (V = hL||hR, bf16), 8 MFMA/tile.
// Residual: h_out[32][16] = Rc[32x32] @ gate[32x16] + (h_in + rb), 2 MFMA/tile.
// Weights live in registers (A-frags); gates cross layouts via per-wave LDS tile.
__global__ __launch_bounds__(128) void layer_m(
    const float* __restrict__ Hin, float* __restrict__ Hout,
    u16* __restrict__ G,
    const u16* __restrict__ Wc, const u16* __restrict__ Rc,
    const float* __restrict__ sbl, const float* __restrict__ tbl,
    const float* __restrict__ rbl,
    int layer, int d, int len_out, int cw, int clen) {
  __shared__ u16 GT[2][64][40];      // per-wave gate tile [pt][32 gates + pad]
  int tid = threadIdx.x;
  int wv = tid >> 6, lane = tid & 63;
  int pc = lane & 15, kg = lane >> 4;
  int b = blockIdx.y;

  // weight fragments in registers
  bf16x8 AW[4][2], AR[2];
  #pragma unroll
  for (int mt = 0; mt < 4; mt++) {
    AW[mt][0] = *reinterpret_cast<const bf16x8*>(Wc + (mt * 16 + pc) * 64 + kg * 8);
    AW[mt][1] = *reinterpret_cast<const bf16x8*>(Wc + (mt * 16 + pc) * 64 + 32 + kg * 8);
  }
  AR[0] = *reinterpret_cast<const bf16x8*>(Rc + pc * 32 + kg * 8);
  AR[1] = *reinterpret_cast<const bf16x8*>(Rc + (16 + pc) * 32 + kg * 8);

  float sbv[2][4], tbv[2][4], rbv[2][4];
  #pragma unroll
  for (int mt = 0; mt < 2; mt++)
    #pragma unroll
    for (int r = 0; r < 4; r++) {
      int o = mt * 16 + kg * 4 + r;
      sbv[mt][r] = sbl[o];
      tbv[mt][r] = tbl[o];
      rbv[mt][r] = rbl[o];
    }

  const float* hb = Hin + (size_t)b * 32 * cw;
  float* ho = Hout + (size_t)b * 32 * cw;
  int base = blockIdx.x * 128 + wv * 64;

  // ---- pass 1: gates ----
  #pragma unroll
  for (int t = 0; t < 4; t++) {
    int idx = base + t * 16 + pc;
    bool valid = idx < len_out;
    int idc = valid ? idx : len_out - 1;
    int p = cw - len_out + idc;

    union { u16 u[8]; bf16x8 v; } uL, uR;
    #pragma unroll
    for (int j = 0; j < 8; j++) {
      int c = kg * 8 + j;
      uL.u[j] = f2bf(hb[(size_t)c * cw + p - d]);
      uR.u[j] = f2bf(hb[(size_t)c * cw + p]);
    }

    f32x4 cs0 = {0.f, 0.f, 0.f, 0.f}, cs1 = {0.f, 0.f, 0.f, 0.f};
    f32x4 ct0 = {0.f, 0.f, 0.f, 0.f}, ct1 = {0.f, 0.f, 0.f, 0.f};
    cs0 = __builtin_amdgcn_mfma_f32_16x16x32_bf16(AW[0][0], uL.v, cs0, 0, 0, 0);
    cs0 = __builtin_amdgcn_mfma_f32_16x16x32_bf16(AW[0][1], uR.v, cs0, 0, 0, 0);
    cs1 = __builtin_amdgcn_mfma_f32_16x16x32_bf16(AW[1][0], uL.v, cs1, 0, 0, 0);
    cs1 = __builtin_amdgcn_mfma_f32_16x16x32_bf16(AW[1][1], uR.v, cs1, 0, 0, 0);
    ct0 = __builtin_amdgcn_mfma_f32_16x16x32_bf16(AW[2][0], uL.v, ct0, 0, 0, 0);
    ct0 = __builtin_amdgcn_mfma_f32_16x16x32_bf16(AW[2][1], uR.v, ct0, 0, 0, 0);
    ct1 = __builtin_amdgcn_mfma_f32_16x16x32_bf16(AW[3][0], uL.v, ct1, 0, 0, 0);
    ct1 = __builtin_amdgcn_mfma_f32_16x16x32_bf16(AW[3][1], uR.v, ct1, 0, 0, 0);

    u16 gs[2][4];
    #pragma unroll
    for (int r = 0; r < 4; r++) {
      float s0 = cs0[r] + sbv[0][r], t0 = ct0[r] + tbv[0][r];
      float s1 = cs1[r] + sbv[1][r], t1 = ct1[r] + tbv[1][r];
      float g0 = (1.f / (1.f + __expf(-s0))) * (2.f / (1.f + __expf(-2.f * t0)) - 1.f);
      float g1 = (1.f / (1.f + __expf(-s1))) * (2.f / (1.f + __expf(-2.f * t1)) - 1.f);
      gs[0][r] = f2bf(g0);
      gs[1][r] = f2bf(g1);
    }
    uint2 pk0 = {(unsigned)gs[0][0] | ((unsigned)gs[0][1] << 16),
                 (unsigned)gs[0][2] | ((unsigned)gs[0][3] << 16)};
    uint2 pk1 = {(unsigned)gs[1][0] | ((unsigned)gs[1][1] << 16),
                 (unsigned)gs[1][2] | ((unsigned)gs[1][3] << 16)};
    int pl = t * 16 + pc;
    *reinterpret_cast<uint2*>(&GT[wv][pl][kg * 4]) = pk0;
    *reinterpret_cast<uint2*>(&GT[wv][pl][16 + kg * 4]) = pk1;

    if (valid && p >= cw - clen) {
      int n = b * clen + (p - (cw - clen));
      u16* gr = G + (size_t)n * K1 + layer * 32;
      *reinterpret_cast<uint2*>(gr + kg * 4) = pk0;
      *reinterpret_cast<uint2*>(gr + 16 + kg * 4) = pk1;
    }
  }

  // ---- pass 2: residual (same-wave LDS dependency, no barrier needed) ----
  #pragma unroll
  for (int t = 0; t < 4; t++) {
    int idx = base + t * 16 + pc;
    bool valid = idx < len_out;
    int idc = valid ? idx : len_out - 1;
    int p = cw - len_out + idc;

    bf16x8 bg = *reinterpret_cast<const bf16x8*>(&GT[wv][t * 16 + pc][kg * 8]);
    f32x4 h0, h1;
    #pragma unroll
    for (int r = 0; r < 4; r++) {
      h0[r] = hb[(size_t)(kg * 4 + r) * cw + p] + rbv[0][r];
      h1[r] = hb[(size_t)(16 + kg * 4 + r) * cw + p] + rbv[1][r];
    }
    f32x4 d0 = __builtin_amdgcn_mfma_f32_16x16x32_bf16(AR[0], bg, h0, 0, 0, 0);
    f32x4 d1 = __builtin_amdgcn_mfma_f32_16x16x32_bf16(AR[1], bg, h1, 0, 0, 0);
    if (valid) {
      #pragma unroll
      for (int r = 0; r < 4; r++) {
        ho[(size_t)(kg * 4 + r) * cw + p] = d0[r];
        ho[(size_t)(16 + kg * 4 + r) * cw + p] = d1[r];
      }
    }
  }
}

// ---------- bf16 MFMA GEMM: Out[m][n] = bf16(elu(sum_k A[m][k]*B[k][n] + bias[m])) ----------
// grid: (m-tiles, n-tiles) -- m fastest so co-resident blocks share the B n-panel.
__global__ __launch_bounds__(256) void gemm_k(
    const u16* __restrict__ A, const u16* __restrict__ B,
    const float* __restrict__ bias, u16* __restrict__ Out,
    int N, int K, int BT) {
  __shared__ u16 As[128][40];
  __shared__ u16 Bs[128][40];
  int tid = threadIdx.x;
  int m0 = blockIdx.x * 128, n0 = blockIdx.y * 128;
  int lane = tid & 63, w = tid >> 6;
  int wm = w >> 1, wn = w & 1;

  f32x4 acc[4][4];
  #pragma unroll
  for (int i = 0; i < 4; i++)
    #pragma unroll
    for (int j = 0; j < 4; j++) acc[i][j] = f32x4{0.f, 0.f, 0.f, 0.f};

  for (int k0 = 0; k0 < K; k0 += 32) {
    {
      int r = tid >> 1, half = tid & 1;
      const uint4* asrc = reinterpret_cast<const uint4*>(A + (size_t)(m0 + r) * K + k0 + half * 16);
      uint4 a0 = asrc[0], a1 = asrc[1];
      *reinterpret_cast<uint4*>(&As[r][half * 16]) = a0;
      *reinterpret_cast<uint4*>(&As[r][half * 16 + 8]) = a1;
    }
    if (BT) {
      int r = tid >> 1, half = tid & 1;
      int nr = n0 + r;
      uint4 b0 = {0, 0, 0, 0}, b1 = {0, 0, 0, 0};
      if (nr < N) {
        const uint4* bsrc = reinterpret_cast<const uint4*>(B + (size_t)nr * K + k0 + half * 16);
        b0 = bsrc[0]; b1 = bsrc[1];
      }
      *reinterpret_cast<uint4*>(&Bs[r][half * 16]) = b0;
      *reinterpret_cast<uint4*>(&Bs[r][half * 16 + 8]) = b1;
    } else {
      int kk = tid >> 3, seg = tid & 7;
      int nbase = n0 + seg * 16;
      const u16* bsrc = B + (size_t)(k0 + kk) * N + nbase;
      u16 tmp[16];
      if (nbase + 16 <= N) {
        const uint2* q = reinterpret_cast<const uint2*>(bsrc);
        uint2 v0 = q[0], v1 = q[1], v2 = q[2], v3 = q[3];
        tmp[0] = v0.x & 0xffff; tmp[1] = v0.x >> 16; tmp[2] = v0.y & 0xffff; tmp[3] = v0.y >> 16;
        tmp[4] = v1.x & 0xffff; tmp[5] = v1.x >> 16; tmp[6] = v1.y & 0xffff; tmp[7] = v1.y >> 16;
        tmp[8] = v2.x & 0xffff; tmp[9] = v2.x >> 16; tmp[10] = v2.y & 0xffff; tmp[11] = v2.y >> 16;
        tmp[12] = v3.x & 0xffff; tmp[13] = v3.x >> 16; tmp[14] = v3.y & 0xffff; tmp[15] = v3.y >> 16;
      } else {
        #pragma unroll
        for (int e = 0; e < 16; e++) tmp[e] = (nbase + e < N) ? bsrc[e] : (u16)0;
      }
      #pragma unroll
      for (int e = 0; e < 16; e++) Bs[seg * 16 + e][kk] = tmp[e];
    }
    __syncthreads();

    int row16 = lane & 15, kg = lane >> 4;
    bf16x8 af[4], bfr[4];
    #pragma unroll
    for (int mf = 0; mf < 4; mf++)
      af[mf] = *reinterpret_cast<const bf16x8*>(&As[wm * 64 + mf * 16 + row16][kg * 8]);
    #pragma unroll
    for (int nf = 0; nf < 4; nf++)
      bfr[nf] = *reinterpret_cast<const bf16x8*>(&Bs[wn * 64 + nf * 16 + row16][kg * 8]);
    #pragma unroll
    for (int mf = 0; mf < 4; mf++)
      #pragma unroll
      for (int nf = 0; nf < 4; nf++)
        acc[mf][nf] = __builtin_amdgcn_mfma_f32_16x16x32_bf16(af[mf], bfr[nf], acc[mf][nf], 0, 0, 0);
    __syncthreads();
  }

  #pragma unroll
  for (int mf = 0; mf < 4; mf++) {
    #pragma unroll
    for (int nf = 0; nf < 4; nf++) {
      #pragma unroll
      for (int r = 0; r < 4; r++) {
        int row = m0 + wm * 64 + mf * 16 + (lane >> 4) * 4 + r;
        int col = n0 + wn * 64 + nf * 16 + (lane & 15);
        float v = acc[mf][nf][r] + bias[row];
        float e = v > 0.f ? v : expm1f(v);
        if (col < N) Out[(size_t)row * N + col] = f2bf(e);
      }
    }
  }
}

// ---------- final: out[b*LOUT + t0 + tc] = post2_w . E2[:, n] + post2_b ----------
__global__ __launch_bounds__(256) void final_k(
    const u16* __restrict__ E2, const float* __restrict__ w,
    const float* __restrict__ bptr, float* __restrict__ out,
    int Nc, int clen, int t0) {
  int n = blockIdx.x * 256 + threadIdx.x;
  if (n >= Nc) return;
  float acc = bptr[0];
  #pragma unroll 8
  for (int c = 0; c < 512; c++) acc += w[c] * bf2f(E2[(size_t)c * Nc + n]);
  int b = n / clen, tc = n - b * clen;
  out[(size_t)b * LOUT + t0 + tc] = acc;
}

extern "C" void kernel_launch(void* const* d_in, const int* in_sizes, int n_in,
                              void* d_out, int out_size, void* d_ws, size_t ws_size,
                              hipStream_t stream) {
  const float* input   = (const float*)d_in[0];
  const float* from_w  = (const float*)d_in[1];
  const float* from_b  = (const float*)d_in[2];
  const float* sig_w   = (const float*)d_in[3];
  const float* sig_b   = (const float*)d_in[4];
  const float* tan_w   = (const float*)d_in[5];
  const float* tan_b   = (const float*)d_in[6];
  const float* skip_w  = (const float*)d_in[7];
  const float* skip_b  = (const float*)d_in[8];
  const float* res_w   = (const float*)d_in[9];
  const float* res_b   = (const float*)d_in[10];
  const float* post1_w = (const float*)d_in[11];
  const float* post1_b = (const float*)d_in[12];
  const float* post2_w = (const float*)d_in[13];
  const float* post2_b = (const float*)d_in[14];

  auto al = [](size_t x) { return (x + 255) & ~(size_t)255; };
  size_t oW  = 0;
  size_t oP1 = oW  + al((size_t)512 * K1 * 2);
  size_t oB  = oP1 + al((size_t)512 * 512 * 2);
  size_t oWC = oB  + al((size_t)512 * 4);
  size_t oRC = oWC + al((size_t)NLAYER * 64 * 64 * 2);
  size_t wend = oRC + al((size_t)NLAYER * 32 * 32 * 2);

  int NC = 32, CL = 0;
  size_t oH0 = wend, oH1 = wend, oG = wend, oE = wend;
  const int cand[6] = {1, 2, 4, 8, 16, 32};
  for (int ci = 0; ci < 6; ci++) {
    int nc = cand[ci];
    int cl = (LOUT + nc - 1) / nc;
    int cw = cl + SUMD;
    size_t hB = al((size_t)NB * 32 * cw * 4);
    size_t gB = al((size_t)NB * cl * K1 * 2);
    size_t eB = al((size_t)512 * NB * cl * 2);
    size_t need = wend + 2 * hB + gB + eB;
    if (need <= ws_size || nc == 32) {
      NC = nc; CL = cl;
      oH0 = wend; oH1 = oH0 + hB; oG = oH1 + hB; oE = oG + gB;
      break;
    }
  }

  char* ws = (char*)d_ws;
  u16*   Wskip = (u16*)(ws + oW);
  u16*   P1    = (u16*)(ws + oP1);
  float* biasS = (float*)(ws + oB);
  u16*   WC    = (u16*)(ws + oWC);
  u16*   RC    = (u16*)(ws + oRC);
  float* H0    = (float*)(ws + oH0);
  float* H1    = (float*)(ws + oH1);
  u16*   G     = (u16*)(ws + oG);
  u16*   E     = (u16*)(ws + oE);
  u16*   E2    = (u16*)(ws + oG);   // reuse G (dead after GEMM1)

  int prep_items = 512 * K1 + 512 * 512 + 512 + NLAYER * 64 * 64 + NLAYER * 32 * 32;
  prep_k<<<(prep_items + 255) / 256, 256, 0, stream>>>(
      skip_w, skip_b, post1_w, sig_w, tan_w, res_w, Wskip, P1, biasS, WC, RC);

  int dils[NLAYER];
  for (int rep = 0; rep < 5; rep++)
    for (int j = 0; j < 10; j++) dils[rep * 10 + j] = 1 << j;

  for (int c = 0; c < NC; c++) {
    int t0 = c * CL;
    if (t0 >= LOUT) break;
    int clen = LOUT - t0 < CL ? LOUT - t0 : CL;
    int cw = clen + SUMD;

    init_h<<<dim3((cw + 255) / 256, NB), 256, 0, stream>>>(input, from_w, from_b, H0, t0, cw);

    int len = cw;
    float* a = H0;
    float* b = H1;
    for (int i = 0; i < NLAYER; i++) {
      int d = dils[i];
      int lo = len - d;
      layer_m<<<dim3((lo + 127) / 128, NB), 128, 0, stream>>>(
          a, b, G, WC + (size_t)i * 4096, RC + (size_t)i * 1024,
          sig_b + i * 32, tan_b + i * 32, res_b + i * 32,
          i, d, lo, cw, clen);
      len = lo;
      float* t = a; a = b; b = t;
    }

    int Nc = NB * clen;
    gemm_k<<<dim3(MSKIP / 128, (Nc + 127) / 128), 256, 0, stream>>>(Wskip, G, biasS, E, Nc, K1, 1);
    gemm_k<<<dim3(MSKIP / 128, (Nc + 127) / 128), 256, 0, stream>>>(P1, E, post1_b, E2, Nc, 512, 0);

    final_k<<<(Nc + 255) / 256, 256, 0, stream>>>(E2, post2_w, post2_b, (float*)d_out, Nc, clen, t0);
  }
}

// Round 5
// 831.754 us; speedup vs baseline: 5.0467x; 1.1899x over previous
//
#include <hip/hip_runtime.h>
#include <hip/hip_bf16.h>

#define TLEN 16384
#define NB 4
#define NLAYER 50
#define SUMD 5115
#define LOUT 11269                  // TLEN - SUMD
#define K1 (NLAYER * 32)            // 1600
#define MSKIP 512

typedef unsigned short u16;
typedef __attribute__((ext_vector_type(4))) float f32x4;
typedef __attribute__((ext_vector_type(8))) __bf16 bf16x8;

__device__ __forceinline__ u16 f2bf(float f) {
  __hip_bfloat16 h = __float2bfloat16(f);
  return *reinterpret_cast<u16*>(&h);
}
__device__ __forceinline__ float bf2f(u16 u) {
  __hip_bfloat16 h = *reinterpret_cast<__hip_bfloat16*>(&u);
  return __bfloat162float(h);
}

// ---------- prep: convert/pack weights (once per call) ----------
__global__ __launch_bounds__(256) void prep_k(
    const float* __restrict__ skip_w, const float* __restrict__ skip_b,
    const float* __restrict__ post1_w,
    const float* __restrict__ sig_w, const float* __restrict__ tan_w,
    const float* __restrict__ res_w,
    u16* __restrict__ Wskip, u16* __restrict__ P1, float* __restrict__ biasS,
    u16* __restrict__ WC, u16* __restrict__ RC) {
  int t = blockIdx.x * 256 + threadIdx.x;
  const int n1 = 512 * K1;                 // 819200
  const int n2 = n1 + 512 * 512;           // +262144
  const int n3 = n2 + 512;
  const int n4 = n3 + NLAYER * 64 * 64;    // +204800
  const int n5 = n4 + NLAYER * 32 * 32;    // +51200
  if (t < n1) {
    int m = t / K1, k = t - m * K1;
    int i = k >> 5, c = k & 31;
    Wskip[t] = f2bf(skip_w[((size_t)i * 512 + m) * 32 + c]);
  } else if (t < n2) {
    int z = t - n1;
    P1[z] = f2bf(post1_w[z]);
  } else if (t < n3) {
    int c = t - n2;
    float s = 0.f;
    for (int i = 0; i < NLAYER; i++) s += skip_b[i * 512 + c];
    biasS[c] = s;
  } else if (t < n4) {
    int z = t - n3;
    int l = z >> 12, rem = z & 4095, o = rem >> 6, k = rem & 63;
    int c = k & 31, lr = k >> 5;
    float v;
    if (o < 32) v = sig_w[(((size_t)l * 32 + o) * 32 + c) * 2 + lr];
    else        v = tan_w[(((size_t)l * 32 + (o - 32)) * 32 + c) * 2 + lr];
    WC[z] = f2bf(v);
  } else if (t < n5) {
    int z = t - n4;
    int l = z >> 10, rem = z & 1023, o = rem >> 5, c = rem & 31;
    RC[z] = f2bf(res_w[((size_t)l * 32 + o) * 32 + c]);
  }
}

// ---------- h0 = from_w @ input^T + from_b, over window [t0, t0+cw) ----------
__global__ __launch_bounds__(256) void init_h(
    const float* __restrict__ inp, const float* __restrict__ fw,
    const float* __restrict__ fb, float* __restrict__ H, int t0, int cw) {
  int b = blockIdx.y;
  int p = blockIdx.x * 256 + threadIdx.x;
  if (p >= cw) return;
  const float* ip = inp + ((size_t)b * TLEN + t0 + p) * 8;
  float4 x0 = *reinterpret_cast<const float4*>(ip);
  float4 x1 = *reinterpret_cast<const float4*>(ip + 4);
  float x[8] = {x0.x, x0.y, x0.z, x0.w, x1.x, x1.y, x1.z, x1.w};
  float* hb = H + (size_t)b * 32 * cw;
  #pragma unroll
  for (int r = 0; r < 32; r++) {
    float acc = fb[r];
    #pragma unroll
    for (int f = 0; f < 8; f++) acc += fw[r * 8 + f] * x[f];
    hb[(size_t)r * cw + p] = acc;
  }
}

// ---------- one WaveNet layer via MFMA: 16 points per wave (4 waves/SIMD TLP) ----------
// Gates: S/T[64][16] = Wc[64x64] @ V[64x16] (V = hL||hR bf16), 8 MFMA.
// Residual: h_out[32][16] = Rc[32x32] @ gate[32x16] + (h_in + rb), 2 MFMA.
// hR crosses pass1(B-frag layout) -> pass2(C layout) via fp32 LDS stash.
__global__ __launch_bounds__(256, 4) void layer_m(
    const float* __restrict__ Hin, float* __restrict__ Hout,
    u16* __restrict__ G,
    const u16* __restrict__ Wc, const u16* __restrict__ Rc,
    const float* __restrict__ sbl, const float* __restrict__ tbl,
    const float* __restrict__ rbl,
    int layer, int d, int len_out, int cw, int clen) {
  __shared__ u16 GT[4][16][40];      // per-wave gate tile [pt][32 + pad]
  __shared__ float HRT[4][16][35];   // per-wave fp32 hR tile [pt][32 + pad]
  int tid = threadIdx.x;
  int wv = tid >> 6, lane = tid & 63;
  int pc = lane & 15, kg = lane >> 4;
  int b = blockIdx.y;

  // weight fragments in registers (L2-broadcast loads, same for all waves)
  bf16x8 AW[4][2], AR[2];
  #pragma unroll
  for (int mt = 0; mt < 4; mt++) {
    AW[mt][0] = *reinterpret_cast<const bf16x8*>(Wc + (mt * 16 + pc) * 64 + kg * 8);
    AW[mt][1] = *reinterpret_cast<const bf16x8*>(Wc + (mt * 16 + pc) * 64 + 32 + kg * 8);
  }
  AR[0] = *reinterpret_cast<const bf16x8*>(Rc + pc * 32 + kg * 8);
  AR[1] = *reinterpret_cast<const bf16x8*>(Rc + (16 + pc) * 32 + kg * 8);

  float4 sbv0 = *reinterpret_cast<const float4*>(sbl + kg * 4);
  float4 sbv1 = *reinterpret_cast<const float4*>(sbl + 16 + kg * 4);
  float4 tbv0 = *reinterpret_cast<const float4*>(tbl + kg * 4);
  float4 tbv1 = *reinterpret_cast<const float4*>(tbl + 16 + kg * 4);
  float4 rbv0 = *reinterpret_cast<const float4*>(rbl + kg * 4);
  float4 rbv1 = *reinterpret_cast<const float4*>(rbl + 16 + kg * 4);

  const float* hb = Hin + (size_t)b * 32 * cw;
  float* ho = Hout + (size_t)b * 32 * cw;

  int idx = blockIdx.x * 64 + wv * 16 + pc;
  bool valid = idx < len_out;
  int idc = valid ? idx : len_out - 1;
  int p = cw - len_out + idc;

  // ---- load h, convert to bf16 frags, stash fp32 hR in LDS ----
  union { u16 u[8]; bf16x8 v; } uL, uR;
  #pragma unroll
  for (int j = 0; j < 8; j++) {
    int c = kg * 8 + j;
    float lv = hb[(size_t)c * cw + p - d];
    float rv = hb[(size_t)c * cw + p];
    uL.u[j] = f2bf(lv);
    uR.u[j] = f2bf(rv);
    HRT[wv][pc][c] = rv;
  }

  // ---- gates ----
  f32x4 cs0 = {0.f, 0.f, 0.f, 0.f}, cs1 = {0.f, 0.f, 0.f, 0.f};
  f32x4 ct0 = {0.f, 0.f, 0.f, 0.f}, ct1 = {0.f, 0.f, 0.f, 0.f};
  cs0 = __builtin_amdgcn_mfma_f32_16x16x32_bf16(AW[0][0], uL.v, cs0, 0, 0, 0);
  cs0 = __builtin_amdgcn_mfma_f32_16x16x32_bf16(AW[0][1], uR.v, cs0, 0, 0, 0);
  cs1 = __builtin_amdgcn_mfma_f32_16x16x32_bf16(AW[1][0], uL.v, cs1, 0, 0, 0);
  cs1 = __builtin_amdgcn_mfma_f32_16x16x32_bf16(AW[1][1], uR.v, cs1, 0, 0, 0);
  ct0 = __builtin_amdgcn_mfma_f32_16x16x32_bf16(AW[2][0], uL.v, ct0, 0, 0, 0);
  ct0 = __builtin_amdgcn_mfma_f32_16x16x32_bf16(AW[2][1], uR.v, ct0, 0, 0, 0);
  ct1 = __builtin_amdgcn_mfma_f32_16x16x32_bf16(AW[3][0], uL.v, ct1, 0, 0, 0);
  ct1 = __builtin_amdgcn_mfma_f32_16x16x32_bf16(AW[3][1], uR.v, ct1, 0, 0, 0);

  u16 gs0[4], gs1[4];
  {
    float sb4[4] = {sbv0.x, sbv0.y, sbv0.z, sbv0.w};
    float sb4b[4] = {sbv1.x, sbv1.y, sbv1.z, sbv1.w};
    float tb4[4] = {tbv0.x, tbv0.y, tbv0.z, tbv0.w};
    float tb4b[4] = {tbv1.x, tbv1.y, tbv1.z, tbv1.w};
    #pragma unroll
    for (int r = 0; r < 4; r++) {
      float s0 = cs0[r] + sb4[r], t0 = ct0[r] + tb4[r];
      float s1 = cs1[r] + sb4b[r], t1 = ct1[r] + tb4b[r];
      float g0 = (1.f / (1.f + __expf(-s0))) * (2.f / (1.f + __expf(-2.f * t0)) - 1.f);
      float g1 = (1.f / (1.f + __expf(-s1))) * (2.f / (1.f + __expf(-2.f * t1)) - 1.f);
      gs0[r] = f2bf(g0);
      gs1[r] = f2bf(g1);
    }
  }
  uint2 pk0 = {(unsigned)gs0[0] | ((unsigned)gs0[1] << 16),
               (unsigned)gs0[2] | ((unsigned)gs0[3] << 16)};
  uint2 pk1 = {(unsigned)gs1[0] | ((unsigned)gs1[1] << 16),
               (unsigned)gs1[2] | ((unsigned)gs1[3] << 16)};
  *reinterpret_cast<uint2*>(&GT[wv][pc][kg * 4]) = pk0;
  *reinterpret_cast<uint2*>(&GT[wv][pc][16 + kg * 4]) = pk1;

  if (valid && p >= cw - clen) {
    int n = b * clen + (p - (cw - clen));
    u16* gr = G + (size_t)n * K1 + layer * 32;
    *reinterpret_cast<uint2*>(gr + kg * 4) = pk0;
    *reinterpret_cast<uint2*>(gr + 16 + kg * 4) = pk1;
  }

  // ---- residual (same-wave LDS dependency; compiler inserts lgkmcnt) ----
  bf16x8 bg = *reinterpret_cast<const bf16x8*>(&GT[wv][pc][kg * 8]);
  f32x4 h0, h1;
  {
    float rb4[4] = {rbv0.x, rbv0.y, rbv0.z, rbv0.w};
    float rb4b[4] = {rbv1.x, rbv1.y, rbv1.z, rbv1.w};
    #pragma unroll
    for (int r = 0; r < 4; r++) {
      h0[r] = HRT[wv][pc][kg * 4 + r] + rb4[r];
      h1[r] = HRT[wv][pc][16 + kg * 4 + r] + rb4b[r];
    }
  }
  f32x4 d0 = __builtin_amdgcn_mfma_f32_16x16x32_bf16(AR[0], bg, h0, 0, 0, 0);
  f32x4 d1 = __builtin_amdgcn_mfma_f32_16x16x32_bf16(AR[1], bg, h1, 0, 0, 0);
  if (valid) {
    #pragma unroll
    for (int r = 0; r < 4; r++) {
      ho[(size_t)(kg * 4 + r) * cw + p] = d0[r];
      ho[(size_t)(16 + kg * 4 + r) * cw + p] = d1[r];
    }
  }
}

// ---------- bf16 MFMA GEMM, BK=64, XCD-swizzled 1-D grid ----------
// A: [512][K] row-major bf16. B: [N][K] row-major bf16 (BT).
// Out: TRANSPOSED [N][512] bf16 = elu(A@B^T + bias[m]).
__global__ __launch_bounds__(256) void gemm_k(
    const u16* __restrict__ A, const u16* __restrict__ B,
    const float* __restrict__ bias, u16* __restrict__ Out,
    int N, int K) {
  __shared__ u16 As[128][72];
  __shared__ u16 Bs[128][72];
  int tid = threadIdx.x;

  // bijective XCD swizzle (m204): contiguous wg-chunks per XCD
  int nwg = gridDim.x;
  int orig = blockIdx.x;
  int q = nwg >> 3, r8 = nwg & 7, xcd = orig & 7, sl = orig >> 3;
  int wg = (xcd < r8 ? xcd * (q + 1) : r8 * (q + 1) + (xcd - r8) * q) + sl;
  int m0 = (wg & 3) * 128;           // m fastest within an XCD chunk -> B panel shared in-XCD
  int n0 = (wg >> 2) * 128;

  int lane = tid & 63, w = tid >> 6;
  int wm = w >> 1, wn = w & 1;

  f32x4 acc[4][4];
  #pragma unroll
  for (int i = 0; i < 4; i++)
    #pragma unroll
    for (int j = 0; j < 4; j++) acc[i][j] = f32x4{0.f, 0.f, 0.f, 0.f};

  int rS = tid >> 1, qS = tid & 1;   // 2 threads/row, 32 cols (64B) each
  for (int k0 = 0; k0 < K; k0 += 64) {
    {
      const uint4* asrc = reinterpret_cast<const uint4*>(A + (size_t)rS * K + k0 + qS * 32);
      uint4 a0 = asrc[0], a1 = asrc[1], a2 = asrc[2], a3 = asrc[3];
      int mr = m0 + rS;  (void)mr;
      const uint4* asrc2 = reinterpret_cast<const uint4*>(A + (size_t)(m0 + rS) * K + k0 + qS * 32);
      a0 = asrc2[0]; a1 = asrc2[1]; a2 = asrc2[2]; a3 = asrc2[3];
      *reinterpret_cast<uint4*>(&As[rS][qS * 32]) = a0;
      *reinterpret_cast<uint4*>(&As[rS][qS * 32 + 8]) = a1;
      *reinterpret_cast<uint4*>(&As[rS][qS * 32 + 16]) = a2;
      *reinterpret_cast<uint4*>(&As[rS][qS * 32 + 24]) = a3;
    }
    {
      int nr = n0 + rS;
      uint4 b0 = {0,0,0,0}, b1 = {0,0,0,0}, b2 = {0,0,0,0}, b3 = {0,0,0,0};
      if (nr < N) {
        const uint4* bsrc = reinterpret_cast<const uint4*>(B + (size_t)nr * K + k0 + qS * 32);
        b0 = bsrc[0]; b1 = bsrc[1]; b2 = bsrc[2]; b3 = bsrc[3];
      }
      *reinterpret_cast<uint4*>(&Bs[rS][qS * 32]) = b0;
      *reinterpret_cast<uint4*>(&Bs[rS][qS * 32 + 8]) = b1;
      *reinterpret_cast<uint4*>(&Bs[rS][qS * 32 + 16]) = b2;
      *reinterpret_cast<uint4*>(&Bs[rS][qS * 32 + 24]) = b3;
    }
    __syncthreads();

    int row16 = lane & 15, kg = lane >> 4;
    #pragma unroll
    for (int s = 0; s < 2; s++) {
      bf16x8 af[4], bfr[4];
      #pragma unroll
      for (int mf = 0; mf < 4; mf++)
        af[mf] = *reinterpret_cast<const bf16x8*>(&As[wm * 64 + mf * 16 + row16][s * 32 + kg * 8]);
      #pragma unroll
      for (int nf = 0; nf < 4; nf++)
        bfr[nf] = *reinterpret_cast<const bf16x8*>(&Bs[wn * 64 + nf * 16 + row16][s * 32 + kg * 8]);
      #pragma unroll
      for (int mf = 0; mf < 4; mf++)
        #pragma unroll
        for (int nf = 0; nf < 4; nf++)
          acc[mf][nf] = __builtin_amdgcn_mfma_f32_16x16x32_bf16(af[mf], bfr[nf], acc[mf][nf], 0, 0, 0);
    }
    __syncthreads();
  }

  // epilogue: bias + elu -> bf16, stored TRANSPOSED: Out[col][row0..row0+3]
  #pragma unroll
  for (int mf = 0; mf < 4; mf++) {
    int rowb = m0 + wm * 64 + mf * 16 + (lane >> 4) * 4;
    float b0 = bias[rowb], b1 = bias[rowb + 1], b2 = bias[rowb + 2], b3 = bias[rowb + 3];
    #pragma unroll
    for (int nf = 0; nf < 4; nf++) {
      int col = n0 + wn * 64 + nf * 16 + (lane & 15);
      if (col < N) {
        float v0 = acc[mf][nf][0] + b0, v1 = acc[mf][nf][1] + b1;
        float v2 = acc[mf][nf][2] + b2, v3 = acc[mf][nf][3] + b3;
        v0 = v0 > 0.f ? v0 : expm1f(v0);
        v1 = v1 > 0.f ? v1 : expm1f(v1);
        v2 = v2 > 0.f ? v2 : expm1f(v2);
        v3 = v3 > 0.f ? v3 : expm1f(v3);
        uint2 pk = {(unsigned)f2bf(v0) | ((unsigned)f2bf(v1) << 16),
                    (unsigned)f2bf(v2) | ((unsigned)f2bf(v3) << 16)};
        *reinterpret_cast<uint2*>(Out + (size_t)col * 512 + rowb) = pk;
      }
    }
  }
}

// ---------- final: out over E2 [N][512]; 4 lanes per point ----------
__global__ __launch_bounds__(256) void final_k(
    const u16* __restrict__ E2, const float* __restrict__ w,
    const float* __restrict__ bptr, float* __restrict__ out,
    int Nc, int clen, int t0) {
  int gid = blockIdx.x * 256 + threadIdx.x;
  int n = gid >> 2, qq = gid & 3;
  if (n >= Nc) return;
  const uint4* row = reinterpret_cast<const uint4*>(E2 + (size_t)n * 512 + qq * 128);
  const float4* wq = reinterpret_cast<const float4*>(w + qq * 128);
  float acc = 0.f;
  #pragma unroll 4
  for (int c8 = 0; c8 < 16; c8++) {
    uint4 v = row[c8];
    float4 w0 = wq[c8 * 2], w1 = wq[c8 * 2 + 1];
    acc += w0.x * bf2f(v.x & 0xffff) + w0.y * bf2f(v.x >> 16)
         + w0.z * bf2f(v.y & 0xffff) + w0.w * bf2f(v.y >> 16)
         + w1.x * bf2f(v.z & 0xffff) + w1.y * bf2f(v.z >> 16)
         + w1.z * bf2f(v.w & 0xffff) + w1.w * bf2f(v.w >> 16);
  }
  acc += __shfl_xor(acc, 1);
  acc += __shfl_xor(acc, 2);
  if (qq == 0) {
    int b = n / clen, tc = n - b * clen;
    out[(size_t)b * LOUT + t0 + tc] = acc + bptr[0];
  }
}

extern "C" void kernel_launch(void* const* d_in, const int* in_sizes, int n_in,
                              void* d_out, int out_size, void* d_ws, size_t ws_size,
                              hipStream_t stream) {
  const float* input   = (const float*)d_in[0];
  const float* from_w  = (const float*)d_in[1];
  const float* from_b  = (const float*)d_in[2];
  const float* sig_w   = (const float*)d_in[3];
  const float* sig_b   = (const float*)d_in[4];
  const float* tan_w   = (const float*)d_in[5];
  const float* tan_b   = (const float*)d_in[6];
  const float* skip_w  = (const float*)d_in[7];
  const float* skip_b  = (const float*)d_in[8];
  const float* res_w   = (const float*)d_in[9];
  const float* res_b   = (const float*)d_in[10];
  const float* post1_w = (const float*)d_in[11];
  const float* post1_b = (const float*)d_in[12];
  const float* post2_w = (const float*)d_in[13];
  const float* post2_b = (const float*)d_in[14];

  auto al = [](size_t x) { return (x + 255) & ~(size_t)255; };
  size_t oW  = 0;
  size_t oP1 = oW  + al((size_t)512 * K1 * 2);
  size_t oB  = oP1 + al((size_t)512 * 512 * 2);
  size_t oWC = oB  + al((size_t)512 * 4);
  size_t oRC = oWC + al((size_t)NLAYER * 64 * 64 * 2);
  size_t wend = oRC + al((size_t)NLAYER * 32 * 32 * 2);

  int NC = 32, CL = 0;
  size_t oH0 = wend, oH1 = wend, oG = wend, oE = wend;
  const int cand[6] = {1, 2, 4, 8, 16, 32};
  for (int ci = 0; ci < 6; ci++) {
    int nc = cand[ci];
    int cl = (LOUT + nc - 1) / nc;
    int cw = cl + SUMD;
    size_t hB = al((size_t)NB * 32 * cw * 4);
    size_t gB = al((size_t)NB * cl * K1 * 2);
    size_t eB = al((size_t)512 * NB * cl * 2);
    size_t need = wend + 2 * hB + gB + eB;
    if (need <= ws_size || nc == 32) {
      NC = nc; CL = cl;
      oH0 = wend; oH1 = oH0 + hB; oG = oH1 + hB; oE = oG + gB;
      break;
    }
  }

  char* ws = (char*)d_ws;
  u16*   Wskip = (u16*)(ws + oW);
  u16*   P1    = (u16*)(ws + oP1);
  float* biasS = (float*)(ws + oB);
  u16*   WC    = (u16*)(ws + oWC);
  u16*   RC    = (u16*)(ws + oRC);
  float* H0    = (float*)(ws + oH0);
  float* H1    = (float*)(ws + oH1);
  u16*   G     = (u16*)(ws + oG);
  u16*   E     = (u16*)(ws + oE);
  u16*   E2    = (u16*)(ws + oG);   // reuse G (dead after GEMM1)

  int prep_items = 512 * K1 + 512 * 512 + 512 + NLAYER * 64 * 64 + NLAYER * 32 * 32;
  prep_k<<<(prep_items + 255) / 256, 256, 0, stream>>>(
      skip_w, skip_b, post1_w, sig_w, tan_w, res_w, Wskip, P1, biasS, WC, RC);

  int dils[NLAYER];
  for (int rep = 0; rep < 5; rep++)
    for (int j = 0; j < 10; j++) dils[rep * 10 + j] = 1 << j;

  for (int c = 0; c < NC; c++) {
    int t0 = c * CL;
    if (t0 >= LOUT) break;
    int clen = LOUT - t0 < CL ? LOUT - t0 : CL;
    int cw = clen + SUMD;

    init_h<<<dim3((cw + 255) / 256, NB), 256, 0, stream>>>(input, from_w, from_b, H0, t0, cw);

    int len = cw;
    float* a = H0;
    float* b = H1;
    for (int i = 0; i < NLAYER; i++) {
      int d = dils[i];
      int lo = len - d;
      layer_m<<<dim3((lo + 63) / 64, NB), 256, 0, stream>>>(
          a, b, G, WC + (size_t)i * 4096, RC + (size_t)i * 1024,
          sig_b + i * 32, tan_b + i * 32, res_b + i * 32,
          i, d, lo, cw, clen);
      len = lo;
      float* t = a; a = b; b = t;
    }

    int Nc = NB * clen;
    int ntile = (Nc + 127) / 128;
    gemm_k<<<4 * ntile, 256, 0, stream>>>(Wskip, G, biasS, E, Nc, K1);
    gemm_k<<<4 * ntile, 256, 0, stream>>>(P1, E, post1_b, E2, Nc, 512);

    final_k<<<(4 * Nc + 255) / 256, 256, 0, stream>>>(E2, post2_w, post2_b, (float*)d_out, Nc, clen, t0);
  }
}